// Round 16
// baseline (181.443 us; speedup 1.0000x reference)
//
#include <hip/hip_runtime.h>

#define NSEG 8192           // faces per set
#define NPTS (3 * NSEG)     // 24576 unified points [S | T | R]
#define NSUP 96             // 256-point super-tiles (32 per segment)
#define NXB  384            // 4 blocks (64 i-rows each) per super-tile
#define NYG  13             // y-groups: g<12 -> Y=4g..4g+3; g==12 -> Y=48
#define NB4  (NPTS * 4)     // B8 frag base
#define ZF   (NPTS * 8)     // zero-frag index (K=16..31 padding for 16x16x32)

typedef short bf16x8 __attribute__((ext_vector_type(8)));   // 8 bf16 (4 VGPRs)
typedef float f32x4  __attribute__((ext_vector_type(4)));   // 4 fp32 acc
typedef unsigned short u16;

__device__ __forceinline__ u16 f2bf(float x) {              // RNE f32 -> bf16 bits
    unsigned u = __builtin_bit_cast(unsigned, x);
    return (u16)((u + 0x7FFFu + ((u >> 16) & 1u)) >> 16);
}
__device__ __forceinline__ float bf2f(u16 h) {
    unsigned u = ((unsigned)h) << 16;
    return __builtin_bit_cast(float, u);
}

__device__ __forceinline__ void compute_point(
    int seg, int f,
    const float* __restrict__ sv, const int* __restrict__ si,
    const float* __restrict__ tv, const int* __restrict__ ti,
    const float* __restrict__ rn, const float* __restrict__ rc,
    float& cx, float& cy, float& cz, float& nx, float& ny, float& nz)
{
    if (seg == 2) {
        nx = rn[3*f];   ny = rn[3*f+1]; nz = rn[3*f+2];
        cx = rc[3*f];   cy = rc[3*f+1]; cz = rc[3*f+2];
    } else {
        const float* v  = (seg == 0) ? sv : tv;
        const int*   nd = (seg == 0) ? si : ti;
        int i0 = nd[3*f], i1 = nd[3*f+1], i2 = nd[3*f+2];
        float ax = v[3*i0], ay = v[3*i0+1], az = v[3*i0+2];
        float bx = v[3*i1], by = v[3*i1+1], bz = v[3*i1+2];
        float gx = v[3*i2], gy = v[3*i2+1], gz = v[3*i2+2];
        float ux = ax-bx, uy = ay-by, uz = az-bz;
        float wx = gx-bx, wy = gy-by, wz = gz-bz;
        nx = 0.5f*(uy*wz - uz*wy);
        ny = 0.5f*(uz*wx - ux*wz);
        nz = 0.5f*(ux*wy - uy*wx);
        cx = (ax+bx+gx)*(1.0f/3.0f);
        cy = (ay+by+gy)*(1.0f/3.0f);
        cz = (az+bz+gz)*(1.0f/3.0f);
    }
}

// Feature rows (K=16 bf16), hi/lo split: t = A_t . B_t = 1+|ci-cj|^2 (~1e-3 abs err).
// A-record [at0 at1 an0 an1], B-record [bt0 bt1 bn0 bn1]; frag ZF is all-zero
// (K=16..31 padding read by quads 2,3 of the 16x16x32 MFMA).
// Split grid: blocks 0..95 build A-records, 96..191 B-records (R12-proven).
__global__ void setup_feats(const float* __restrict__ sv, const int* __restrict__ si,
                            const float* __restrict__ tv, const int* __restrict__ ti,
                            const float* __restrict__ rn, const float* __restrict__ rc,
                            u16* __restrict__ ws, float* __restrict__ out) {
    int gid = blockIdx.x * 256 + threadIdx.x;
    bf16x8* A8 = (bf16x8*)ws;
    if (gid == 0) {
        out[0] = 0.0f;                  // d_out poisoned 0xAA before every launch
        bf16x8 z;
        #pragma unroll
        for (int k = 0; k < 8; ++k) z[k] = 0;
        A8[ZF] = z;                     // the shared zero frag
    }
    const int rec = (gid >= NPTS);      // block-uniform (96 blocks per record kind)
    const int p   = rec ? gid - NPTS : gid;
    int seg = p >> 13, f = p & (NSEG - 1);
    float cx, cy, cz, nx, ny, nz;
    compute_point(seg, f, sv, si, tv, ti, rn, rc, cx, cy, cz, nx, ny, nz);

    const u16 ONE = 0x3F80;
    float s = cx*cx + cy*cy + cz*cz;
    u16 chx = f2bf(cx), chy = f2bf(cy), chz = f2bf(cz);
    u16 clx = f2bf(cx - bf2f(chx)), cly = f2bf(cy - bf2f(chy)), clz = f2bf(cz - bf2f(chz));
    u16 sh  = f2bf(s);
    u16 sl  = f2bf(s - bf2f(sh));
    u16 nhx = f2bf(nx), nhy = f2bf(ny), nhz = f2bf(nz);
    u16 nlx = f2bf(nx - bf2f(nhx)), nly = f2bf(ny - bf2f(nhy)), nlz = f2bf(nz - bf2f(nhz));

    bf16x8* B8 = A8 + NB4;
    u16 r0[16], r1[16];
    if (!rec) {
        u16 at[16] = {chx,chy,chz, clx,cly,clz, chx,chy,chz, sh, sl, ONE, ONE, ONE, 0, 0};
        u16 an[16] = {nhx,nhy,nhz, nlx,nly,nlz, nhx,nhy,nhz, 0,0,0,0,0,0,0};
        #pragma unroll
        for (int k = 0; k < 16; ++k) { r0[k] = at[k]; r1[k] = an[k]; }
    } else {
        u16 m2hx = f2bf(-2.0f*bf2f(chx)), m2hy = f2bf(-2.0f*bf2f(chy)), m2hz = f2bf(-2.0f*bf2f(chz));
        u16 m2lx = f2bf(-2.0f*bf2f(clx)), m2ly = f2bf(-2.0f*bf2f(cly)), m2lz = f2bf(-2.0f*bf2f(clz));
        u16 bt[16] = {m2hx,m2hy,m2hz, m2hx,m2hy,m2hz, m2lx,m2ly,m2lz, ONE, ONE, sh, sl, ONE, 0, 0};
        u16 bn[16] = {nhx,nhy,nhz, nhx,nhy,nhz, nlx,nly,nlz, 0,0,0,0,0,0,0};
        #pragma unroll
        for (int k = 0; k < 16; ++k) { r0[k] = bt[k]; r1[k] = bn[k]; }
    }
    bf16x8* dst = rec ? B8 : A8;
    bf16x8 v0, v1, v2, v3;
    #pragma unroll
    for (int k = 0; k < 8; ++k) { v0[k] = (short)r0[k]; v1[k] = (short)r0[k+8];
                                  v2[k] = (short)r1[k]; v3[k] = (short)r1[k+8]; }
    dst[(size_t)p*4+0] = v0; dst[(size_t)p*4+1] = v1;
    dst[(size_t)p*4+2] = v2; dst[(size_t)p*4+3] = v3;
}

// Symmetric-pair kernel on 16x16x32 MFMA (4-reg accumulators -> ~60-reg waves,
// ~8 waves/SIMD vs the 32x32 path's ~100-reg/4.3-wave cap). R8 proved this
// shape's correctness (absmax 0.0); its spill causes are removed here:
// no masked loads (zero-frag via ADDRESS cndmask, exec always full), no frag
// arrays (named-register rotation), (256,4) budget not (256,6).
// Wrapped map over 256-pt super-tiles: (I,J) = (X, (X+Y)%96); mult = 2 except
// Y==0 (diag, once) and Y==48 (both ends) -> 96+96+96*47*2 = 96^2. ✓
// Block = 4 waves x 16 i-rows (i-base = X*256 + (bx&3)*64 + wid*16);
// per y: 16 j-tiles of 16 points. Lane roles: n16 = A-row/B-col, q = k-quad;
// quads 2,3 read the zero frag (K=16..31 padding).
__launch_bounds__(256, 4)
__global__ void energy_mfma(const u16* __restrict__ ws, float* __restrict__ out) {
    const int tid  = threadIdx.x;
    const int lane = tid & 63, wid = tid >> 6;
    const int n16  = lane & 15, q = lane >> 4;    // q in 0..3
    const bool lo2 = (q < 2);                     // quads 0,1 carry real K=0..15

    const int bx  = blockIdx.x;               // 0..383
    const int X   = bx >> 2;                  // super-tile row 0..95
    const int sub = bx & 3;                   // 64-row slice within super-tile
    const int g   = blockIdx.y;               // 0..12
    const int y0   = (g < 12) ? 4*g : 48;
    const int ycnt = (g < 12) ? 4 : 1;
    const int gi = X >> 5;                    // 32 super-tiles per segment

    const float Wt[9] = {1.8f, -0.8f, -1.0f,
                        -0.8f,  1.8f, -1.0f,
                        -1.0f, -1.0f,  2.0f};

    const bf16x8* W8 = (const bf16x8*)ws;

    // persistent A-frags: row m = n16 of this wave's 16-row i-tile, k-quad q
    const int pi = X*256 + sub*64 + wid*16 + n16;
    const bf16x8 at = W8[lo2 ? pi*4 + q     : ZF];
    const bf16x8 an = W8[lo2 ? pi*4 + 2 + q : ZF];

    f32x4 Z = {0.0f, 0.0f, 0.0f, 0.0f};
    const int lofs = n16*4 + q;               // per-lane B frag offset within a j-tile

    float acc = 0.0f;
    for (int yy = 0; yy < ycnt; ++yy) {
        const int y = y0 + yy;
        int J = X + y; if (J >= NSUP) J -= NSUP;
        const float mult = (y == 0 || y == 48) ? 1.0f : 2.0f;
        const float w = Wt[gi*3 + (J >> 5)] * mult;   // block-uniform per y

        const int Jbase = NB4 + J*1024;       // j-tile stride = 16 pts * 4 frags = 64

        // prefetch rotation in named registers (address-selected zero for q>=2)
        bf16x8 btf = W8[lo2 ? Jbase + lofs     : ZF];
        bf16x8 bnf = W8[lo2 ? Jbase + lofs + 2 : ZF];

        float ts0 = 0.0f, ts1 = 0.0f;
        #pragma unroll 4
        for (int jt = 0; jt < 16; ++jt) {
            int jn = Jbase + ((jt < 15) ? (jt + 1) : jt) * 64;   // clamped last
            bf16x8 nbt = W8[lo2 ? jn + lofs     : ZF];
            bf16x8 nbn = W8[lo2 ? jn + lofs + 2 : ZF];

            f32x4 ct = __builtin_amdgcn_mfma_f32_16x16x32_bf16(at, btf, Z, 0, 0, 0);
            f32x4 cn = __builtin_amdgcn_mfma_f32_16x16x32_bf16(an, bnf, Z, 0, 0, 0);

            // batched rcp: one v_rcp per 4 pairs (R8-verified epilogue)
            float q0 = ct[0]*ct[0], q1 = ct[1]*ct[1];
            float q2 = ct[2]*ct[2], q3 = ct[3]*ct[3];
            float s01 = q0*q1, s23 = q2*q3;
            float r   = __builtin_amdgcn_rcpf(s01*s23);
            float u   = __builtin_fmaf(cn[1], q0, cn[0]*q1);
            float v   = __builtin_fmaf(cn[3], q2, cn[2]*q3);
            float num = __builtin_fmaf(v, s01, u*s23);
            if (jt & 1) ts1 = __builtin_fmaf(num, r, ts1);
            else        ts0 = __builtin_fmaf(num, r, ts0);

            btf = nbt; bnf = nbn;
        }
        acc = __builtin_fmaf(w, ts0 + ts1, acc);
    }

    // wave shuffle reduce -> 4 partials -> one atomic per block
    for (int off = 32; off; off >>= 1) acc += __shfl_down(acc, off, 64);
    __shared__ float partial[4];
    if ((tid & 63) == 0) partial[wid] = acc;
    __syncthreads();
    if (tid == 0)
        atomicAdd(out, (partial[0] + partial[1]) + (partial[2] + partial[3]));
}

extern "C" void kernel_launch(void* const* d_in, const int* in_sizes, int n_in,
                              void* d_out, int out_size, void* d_ws, size_t ws_size,
                              hipStream_t stream) {
    const float* sv = (const float*)d_in[0];
    const int*   si = (const int*)d_in[1];
    const float* tv = (const float*)d_in[2];
    const int*   ti = (const int*)d_in[3];
    const float* rn = (const float*)d_in[4];
    const float* rc = (const float*)d_in[5];
    float* out = (float*)d_out;
    u16*   ws  = (u16*)d_ws;                  // (NPTS*8 + 1) frags * 16 B ≈ 3.0 MB

    setup_feats<<<2*NPTS/256, 256, 0, stream>>>(sv, si, tv, ti, rn, rc, ws, out);
    dim3 grid(NXB, NYG);                      // 384 x 13 = 4992 blocks of 256
    energy_mfma<<<grid, 256, 0, stream>>>(ws, out);
}